// Round 1
// baseline (502.711 us; speedup 1.0000x reference)
//
#include <hip/hip_runtime.h>
#include <math.h>

#define SS 256
#define CC 128
#define NH 4
#define HD 32
#define M_TOT (SS*SS)       // 65536
#define NPROJ 516           // 4*128 (q,k,v,g) + 4 (bias heads)
#define HEAD_STRIDE (M_TOT*HD)  // 2097152

// ---------------- LayerNorm ----------------
__global__ __launch_bounds__(128) void ln_kernel(
    const float* __restrict__ x, const float* __restrict__ ln_w,
    const float* __restrict__ ln_b, float* __restrict__ hbuf) {
  int m = blockIdx.x;
  int c = threadIdx.x;
  float v = x[m*CC + c];
  float s = v, s2 = v*v;
  #pragma unroll
  for (int o = 32; o > 0; o >>= 1) {
    s  += __shfl_xor(s, o);
    s2 += __shfl_xor(s2, o);
  }
  __shared__ float red[4];
  int w = c >> 6;
  if ((c & 63) == 0) { red[w*2] = s; red[w*2+1] = s2; }
  __syncthreads();
  s  = red[0] + red[2];
  s2 = red[1] + red[3];
  float mu  = s * (1.0f/CC);
  float var = s2 * (1.0f/CC) - mu*mu;
  float r = rsqrtf(var + 1e-5f);
  hbuf[m*CC + c] = (v - mu) * r * ln_w[c] + ln_b[c];
}

// ---------------- pack weights into one [516][128] buffer ----------------
__global__ __launch_bounds__(256) void pack_w(
    const float* __restrict__ wq, const float* __restrict__ wk,
    const float* __restrict__ wv, const float* __restrict__ wg,
    const float* __restrict__ wb, float* __restrict__ wcomb) {
  int idx = blockIdx.x*256 + threadIdx.x;
  if (idx >= NPROJ*CC) return;
  int n = idx >> 7, kk = idx & 127;
  float val;
  if (n < 128)      val = wq[n*128 + kk];
  else if (n < 256) val = wk[(n-128)*128 + kk];
  else if (n < 384) val = wv[(n-256)*128 + kk];
  else if (n < 512) val = wg[(n-384)*128 + kk];
  else              val = wb[(n-512)*128 + kk];
  wcomb[idx] = val;
}

// ---------------- projection GEMM: [65536 x 128] x [128 x 516] ----------------
// BM=64, BN=64, BK=16, 256 threads, 4x4 per thread
__global__ __launch_bounds__(256) void proj_gemm(
    const float* __restrict__ A, const float* __restrict__ B,
    float* __restrict__ qb, float* __restrict__ kb, float* __restrict__ vb,
    float* __restrict__ gb, float* __restrict__ bias_t) {
  __shared__ float As[16][68];
  __shared__ float Bs[16][68];
  int bm = blockIdx.x * 64;
  int bn = blockIdx.y * 64;
  int tid = threadIdx.x;
  int tr = tid >> 4, tc = tid & 15;
  int lrow = tid >> 2;
  int lk4  = (tid & 3) * 4;
  float acc[4][4] = {};
  for (int k0 = 0; k0 < 128; k0 += 16) {
    float4 a4 = *(const float4*)&A[(bm+lrow)*128 + k0 + lk4];
    float4 b4 = make_float4(0.f,0.f,0.f,0.f);
    int brow = bn + lrow;
    if (brow < NPROJ) b4 = *(const float4*)&B[brow*128 + k0 + lk4];
    __syncthreads();
    As[lk4+0][lrow]=a4.x; As[lk4+1][lrow]=a4.y; As[lk4+2][lrow]=a4.z; As[lk4+3][lrow]=a4.w;
    Bs[lk4+0][lrow]=b4.x; Bs[lk4+1][lrow]=b4.y; Bs[lk4+2][lrow]=b4.z; Bs[lk4+3][lrow]=b4.w;
    __syncthreads();
    #pragma unroll
    for (int kk = 0; kk < 16; kk++) {
      float ar[4], br[4];
      #pragma unroll
      for (int t = 0; t < 4; t++) { ar[t] = As[kk][tr*4+t]; br[t] = Bs[kk][tc*4+t]; }
      #pragma unroll
      for (int ii = 0; ii < 4; ii++)
        #pragma unroll
        for (int jj = 0; jj < 4; jj++)
          acc[ii][jj] += ar[ii]*br[jj];
    }
  }
  #pragma unroll
  for (int ii = 0; ii < 4; ii++) {
    int m = bm + tr*4 + ii;
    #pragma unroll
    for (int jj = 0; jj < 4; jj++) {
      int n = bn + tc*4 + jj;
      if (n >= NPROJ) continue;
      float val = acc[ii][jj];
      if (n < 128) {
        qb[(n>>5)*HEAD_STRIDE + m*HD + (n&31)] = val;
      } else if (n < 256) {
        int nn = n - 128;
        kb[(nn>>5)*HEAD_STRIDE + m*HD + (nn&31)] = val;
      } else if (n < 384) {
        int nn = n - 256;
        vb[(nn>>5)*HEAD_STRIDE + m*HD + (nn&31)] = val;
      } else if (n < 512) {
        int e = n - 384;
        gb[m*128 + e] = 1.0f/(1.0f + __expf(-val));
      } else {
        int hh = n - 512;
        // bias_t[h][k][j]: m encodes (j = m>>8, k = m&255) of the pair
        bias_t[hh*M_TOT + (m&255)*SS + (m>>8)] = val;
      }
    }
  }
}

// ---------------- attention: one block per (i, h) ----------------
__global__ __launch_bounds__(256) void attn_kernel(
    const float* __restrict__ qbuf, const float* __restrict__ kbuf,
    const float* __restrict__ vbuf, const float* __restrict__ bias_t,
    float* __restrict__ obuf) {
  int i  = blockIdx.x;
  int hh = blockIdx.y;
  __shared__ float Ks[SS][HD];
  __shared__ float Vs[SS][HD];
  int tid = threadIdx.x;
  const float* kp = kbuf + hh*HEAD_STRIDE + i*(SS*HD);
  const float* vp = vbuf + hh*HEAD_STRIDE + i*(SS*HD);
  #pragma unroll
  for (int t = 0; t < 8; t++) {
    int idx = t*256 + tid;
    ((float4*)&Ks[0][0])[idx] = ((const float4*)kp)[idx];
    ((float4*)&Vs[0][0])[idx] = ((const float4*)vp)[idx];
  }
  int j = tid;
  float qreg[HD];
  const float* qp = qbuf + hh*HEAD_STRIDE + i*(SS*HD) + j*HD;
  const float scale = 0.17677669529663687f; // 1/sqrt(32)
  #pragma unroll
  for (int d = 0; d < HD; d++) qreg[d] = qp[d] * scale;
  __syncthreads();
  const float* bp = bias_t + hh*M_TOT + j;
  float l = 0.f;
  float oacc[HD] = {};
  for (int kk = 0; kk < SS; kk++) {
    float s = bp[kk*SS];
    #pragma unroll
    for (int d = 0; d < HD; d++) s += qreg[d]*Ks[kk][d];
    float p = __expf(s);
    l += p;
    #pragma unroll
    for (int d = 0; d < HD; d++) oacc[d] += p * Vs[kk][d];
  }
  float rl = 1.0f/l;
  float* op = obuf + (i*SS + j)*128 + hh*HD;
  #pragma unroll
  for (int d = 0; d < HD; d++) op[d] = oacc[d]*rl;
}

// ---------------- gate + output projection: [65536 x 128] x [128 x 128] ----------------
__global__ __launch_bounds__(256) void out_gemm(
    const float* __restrict__ obuf, const float* __restrict__ gbuf,
    const float* __restrict__ wo, float* __restrict__ out) {
  __shared__ float As[16][68];
  __shared__ float Bs[16][68];
  int bm = blockIdx.x * 64;
  int bn = blockIdx.y * 64;
  int tid = threadIdx.x;
  int tr = tid >> 4, tc = tid & 15;
  int lrow = tid >> 2;
  int lk4  = (tid & 3) * 4;
  float acc[4][4] = {};
  for (int k0 = 0; k0 < 128; k0 += 16) {
    float4 a4 = *(const float4*)&obuf[(bm+lrow)*128 + k0 + lk4];
    float4 g4 = *(const float4*)&gbuf[(bm+lrow)*128 + k0 + lk4];
    a4.x *= g4.x; a4.y *= g4.y; a4.z *= g4.z; a4.w *= g4.w;
    float4 b4 = *(const float4*)&wo[(bn+lrow)*128 + k0 + lk4];
    __syncthreads();
    As[lk4+0][lrow]=a4.x; As[lk4+1][lrow]=a4.y; As[lk4+2][lrow]=a4.z; As[lk4+3][lrow]=a4.w;
    Bs[lk4+0][lrow]=b4.x; Bs[lk4+1][lrow]=b4.y; Bs[lk4+2][lrow]=b4.z; Bs[lk4+3][lrow]=b4.w;
    __syncthreads();
    #pragma unroll
    for (int kk = 0; kk < 16; kk++) {
      float ar[4], br[4];
      #pragma unroll
      for (int t = 0; t < 4; t++) { ar[t] = As[kk][tr*4+t]; br[t] = Bs[kk][tc*4+t]; }
      #pragma unroll
      for (int ii = 0; ii < 4; ii++)
        #pragma unroll
        for (int jj = 0; jj < 4; jj++)
          acc[ii][jj] += ar[ii]*br[jj];
    }
  }
  #pragma unroll
  for (int ii = 0; ii < 4; ii++) {
    int m = bm + tr*4 + ii;
    #pragma unroll
    for (int jj = 0; jj < 4; jj++) {
      int n = bn + tc*4 + jj;
      out[m*128 + n] = acc[ii][jj];
    }
  }
}

extern "C" void kernel_launch(void* const* d_in, const int* in_sizes, int n_in,
                              void* d_out, int out_size, void* d_ws, size_t ws_size,
                              hipStream_t stream) {
  const float* x    = (const float*)d_in[0];
  const float* ln_w = (const float*)d_in[1];
  const float* ln_b = (const float*)d_in[2];
  const float* w_bias = (const float*)d_in[3];
  const float* w_q  = (const float*)d_in[4];
  const float* w_k  = (const float*)d_in[5];
  const float* w_v  = (const float*)d_in[6];
  const float* w_g  = (const float*)d_in[7];
  const float* w_o  = (const float*)d_in[8];
  float* out = (float*)d_out;

  float* W = (float*)d_ws;
  float* hbuf   = W;                        // 8388608
  float* qb     = W + 8388608;              // 8388608
  float* kb     = W + 16777216;             // 8388608
  float* vb     = W + 25165824;             // 8388608
  float* gb     = W + 33554432;             // 8388608
  float* bias_t = W + 41943040;             // 262144
  float* wcomb  = W + 42205184;             // 66048
  float* obuf   = hbuf;                     // reuse h after projections

  ln_kernel<<<M_TOT, 128, 0, stream>>>(x, ln_w, ln_b, hbuf);
  pack_w<<<(NPROJ*CC + 255)/256, 256, 0, stream>>>(w_q, w_k, w_v, w_g, w_bias, wcomb);
  proj_gemm<<<dim3(M_TOT/64, (NPROJ+63)/64), 256, 0, stream>>>(hbuf, wcomb, qb, kb, vb, gb, bias_t);
  attn_kernel<<<dim3(SS, NH), 256, 0, stream>>>(qb, kb, vb, bias_t, obuf);
  out_gemm<<<dim3(M_TOT/64, 2), 256, 0, stream>>>(obuf, gb, w_o, out);
}

// Round 2
// 339.687 us; speedup vs baseline: 1.4799x; 1.4799x over previous
//
#include <hip/hip_runtime.h>
#include <hip/hip_bf16.h>
#include <math.h>

#define SS 256
#define CC 128
#define NH 4
#define HD 32
#define M_TOT (SS*SS)       // 65536
#define NPROJ 516           // 4*128 (q,k,v,g) + 4 (bias heads)
#define HEAD_STRIDE (M_TOT*HD)
#define PSTR 72             // padded row stride (elems) for P buffer
#define VSTR 264            // padded row stride (elems) for V^T buffer
#define SCALE 0.17677669529663687f

typedef short short8 __attribute__((ext_vector_type(8)));
typedef float f32x4 __attribute__((ext_vector_type(4)));

static __device__ __forceinline__ unsigned int f2bf(float f) {
  unsigned int u = __builtin_bit_cast(unsigned int, f);
  u += 0x7fffu + ((u >> 16) & 1u);
  return u >> 16;
}

// ---------------- LayerNorm ----------------
__global__ __launch_bounds__(128) void ln_kernel(
    const float* __restrict__ x, const float* __restrict__ ln_w,
    const float* __restrict__ ln_b, float* __restrict__ hbuf) {
  int m = blockIdx.x;
  int c = threadIdx.x;
  float v = x[m*CC + c];
  float s = v, s2 = v*v;
  #pragma unroll
  for (int o = 32; o > 0; o >>= 1) {
    s  += __shfl_xor(s, o);
    s2 += __shfl_xor(s2, o);
  }
  __shared__ float red[4];
  int w = c >> 6;
  if ((c & 63) == 0) { red[w*2] = s; red[w*2+1] = s2; }
  __syncthreads();
  s  = red[0] + red[2];
  s2 = red[1] + red[3];
  float mu  = s * (1.0f/CC);
  float var = s2 * (1.0f/CC) - mu*mu;
  float r = rsqrtf(var + 1e-5f);
  hbuf[m*CC + c] = (v - mu) * r * ln_w[c] + ln_b[c];
}

// ---------------- pack weights into one [516][128] buffer ----------------
__global__ __launch_bounds__(256) void pack_w(
    const float* __restrict__ wq, const float* __restrict__ wk,
    const float* __restrict__ wv, const float* __restrict__ wg,
    const float* __restrict__ wb, float* __restrict__ wcomb) {
  int idx = blockIdx.x*256 + threadIdx.x;
  if (idx >= NPROJ*CC) return;
  int n = idx >> 7, kk = idx & 127;
  float val;
  if (n < 128)      val = wq[n*128 + kk];
  else if (n < 256) val = wk[(n-128)*128 + kk];
  else if (n < 384) val = wv[(n-256)*128 + kk];
  else if (n < 512) val = wg[(n-384)*128 + kk];
  else              val = wb[(n-512)*128 + kk];
  wcomb[idx] = val;
}

// ---------------- projection GEMM: [65536 x 128] x [128 x 516] ----------------
__global__ __launch_bounds__(256) void proj_gemm(
    const float* __restrict__ A, const float* __restrict__ B,
    unsigned short* __restrict__ qb, unsigned short* __restrict__ kb,
    unsigned short* __restrict__ vb, float* __restrict__ gb,
    float* __restrict__ biasF) {
  __shared__ float As[16][68];
  __shared__ float Bs[16][68];
  int bm = blockIdx.x * 64;
  int bn = blockIdx.y * 64;
  int tid = threadIdx.x;
  int tr = tid >> 4, tc = tid & 15;
  int lrow = tid >> 2;
  int lk4  = (tid & 3) * 4;
  float acc[4][4] = {};
  for (int k0 = 0; k0 < 128; k0 += 16) {
    float4 a4 = *(const float4*)&A[(bm+lrow)*128 + k0 + lk4];
    float4 b4 = make_float4(0.f,0.f,0.f,0.f);
    int brow = bn + lrow;
    if (brow < NPROJ) b4 = *(const float4*)&B[brow*128 + k0 + lk4];
    __syncthreads();
    As[lk4+0][lrow]=a4.x; As[lk4+1][lrow]=a4.y; As[lk4+2][lrow]=a4.z; As[lk4+3][lrow]=a4.w;
    Bs[lk4+0][lrow]=b4.x; Bs[lk4+1][lrow]=b4.y; Bs[lk4+2][lrow]=b4.z; Bs[lk4+3][lrow]=b4.w;
    __syncthreads();
    #pragma unroll
    for (int kk = 0; kk < 16; kk++) {
      float ar[4], br[4];
      #pragma unroll
      for (int t = 0; t < 4; t++) { ar[t] = As[kk][tr*4+t]; br[t] = Bs[kk][tc*4+t]; }
      #pragma unroll
      for (int ii = 0; ii < 4; ii++)
        #pragma unroll
        for (int jj = 0; jj < 4; jj++)
          acc[ii][jj] += ar[ii]*br[jj];
    }
  }
  #pragma unroll
  for (int ii = 0; ii < 4; ii++) {
    int m = bm + tr*4 + ii;
    #pragma unroll
    for (int jj = 0; jj < 4; jj++) {
      int n = bn + tc*4 + jj;
      if (n >= NPROJ) continue;
      float val = acc[ii][jj];
      if (n < 128) {
        qb[(size_t)(n>>5)*HEAD_STRIDE + (size_t)m*HD + (n&31)] = (unsigned short)f2bf(val);
      } else if (n < 256) {
        int nn = n - 128;
        kb[(size_t)(nn>>5)*HEAD_STRIDE + (size_t)m*HD + (nn&31)] = (unsigned short)f2bf(val);
      } else if (n < 384) {
        int nn = n - 256;
        vb[(size_t)(nn>>5)*HEAD_STRIDE + (size_t)m*HD + (nn&31)] = (unsigned short)f2bf(val);
      } else if (n < 512) {
        int e = n - 384;
        gb[(size_t)m*128 + e] = 1.0f/(1.0f + __expf(-val));
      } else {
        // tri_bias[hh][ji][ki]; stored in MFMA C-fragment order per 16x16 tile
        int hh = n - 512;
        int ji = m >> 8, ki = m & 255;
        int jt = ji >> 4, q2 = (ji >> 2) & 3, rg = ji & 3;
        int kt = ki >> 4, lf = ki & 15;
        biasF[(size_t)(((hh*16 + jt)*16 + kt) << 8) + (q2*16 + lf)*4 + rg] = val;
      }
    }
  }
}

// ---------------- MFMA attention: one block per (i, h), 4 waves ----------------
__global__ __launch_bounds__(256) void attn_mfma(
    const unsigned short* __restrict__ qb, const unsigned short* __restrict__ kb,
    const unsigned short* __restrict__ vb, const float* __restrict__ biasF,
    float* __restrict__ obuf) {
  __shared__ unsigned short Vt[32*VSTR];       // V^T [d][k], padded
  __shared__ unsigned short Pb[4*64*PSTR];     // per-wave P [j][k], padded
  int i = blockIdx.x, hh = blockIdx.y;
  int tid = threadIdx.x;
  int wv = tid >> 6, lane = tid & 63;
  int quad = lane >> 4, l15 = lane & 15;

  // ---- stage V^T into LDS (thread t owns key row k=t) ----
  {
    const unsigned short* vrow = vb + ((size_t)hh*M_TOT + (size_t)i*SS + tid) * HD;
    const uint4* v4 = (const uint4*)vrow;
    #pragma unroll
    for (int c = 0; c < 4; c++) {
      uint4 r = v4[c];
      unsigned int u[4] = {r.x, r.y, r.z, r.w};
      #pragma unroll
      for (int w = 0; w < 4; w++) {
        int d = c*8 + w*2;
        Vt[d*VSTR + tid]     = (unsigned short)(u[w] & 0xffffu);
        Vt[(d+1)*VSTR + tid] = (unsigned short)(u[w] >> 16);
      }
    }
  }

  // ---- Q fragments (A-layout: lane holds Q[jbase+l15][quad*8..+7]) ----
  const unsigned short* qbase = qb + ((size_t)hh*M_TOT + (size_t)i*SS + wv*64) * HD;
  short8 Qf[4];
  #pragma unroll
  for (int a = 0; a < 4; a++)
    Qf[a] = *(const short8*)(qbase + (a*16 + l15)*HD + quad*8);

  const unsigned short* kbp = kb + ((size_t)hh*M_TOT + (size_t)i*SS) * HD;
  const float* bbase = biasF + (size_t)(hh*16 + wv*4) * 16 * 256;

  const f32x4 fz = {0.f, 0.f, 0.f, 0.f};
  f32x4 Oa[4][2];
  #pragma unroll
  for (int a = 0; a < 4; a++) { Oa[a][0] = fz; Oa[a][1] = fz; }
  float lsum[4][4] = {};

  unsigned short* pw = Pb + wv*64*PSTR;
  int odd = lane & 1;

  __syncthreads();

  for (int it = 0; it < 4; it++) {
    #pragma unroll
    for (int b = 0; b < 4; b++) {
      int kt = it*4 + b;
      short8 Kf = *(const short8*)(kbp + (kt*16 + l15)*HD + quad*8);
      #pragma unroll
      for (int a = 0; a < 4; a++) {
        f32x4 S = __builtin_amdgcn_mfma_f32_16x16x32_bf16(Qf[a], Kf, fz, 0, 0, 0);
        float4 bias = *(const float4*)(bbase + (size_t)((a*16 + kt) << 8) + lane*4);
        float p0 = __expf(S[0]*SCALE + bias.x);
        float p1 = __expf(S[1]*SCALE + bias.y);
        float p2 = __expf(S[2]*SCALE + bias.z);
        float p3 = __expf(S[3]*SCALE + bias.w);
        lsum[a][0] += p0; lsum[a][1] += p1; lsum[a][2] += p2; lsum[a][3] += p3;
        unsigned int b0 = f2bf(p0), b1 = f2bf(p1), b2 = f2bf(p2), b3 = f2bf(p3);
        unsigned int o0 = (unsigned int)__shfl_xor((int)b0, 1);
        unsigned int o1 = (unsigned int)__shfl_xor((int)b1, 1);
        unsigned int o2 = (unsigned int)__shfl_xor((int)b2, 1);
        unsigned int o3 = (unsigned int)__shfl_xor((int)b3, 1);
        // lane-pair pack: even lane writes rows +0,+1; odd lane rows +2,+3
        int jb = a*16 + quad*4;
        int colE = (b*16 + l15) & ~1;
        unsigned int vA = odd ? (o2 | (b2 << 16)) : (b0 | (o0 << 16));
        unsigned int vB = odd ? (o3 | (b3 << 16)) : (b1 | (o1 << 16));
        int rA = jb + (odd ? 2 : 0);
        int rB = jb + (odd ? 3 : 1);
        *(unsigned int*)&pw[rA*PSTR + colE] = vA;
        *(unsigned int*)&pw[rB*PSTR + colE] = vB;
      }
    }
    // P·V for this 64-wide k chunk (wave-private P buffer, no barrier needed)
    #pragma unroll
    for (int kk = 0; kk < 2; kk++) {
      short8 Vf0 = *(const short8*)&Vt[(l15)*VSTR      + it*64 + kk*32 + quad*8];
      short8 Vf1 = *(const short8*)&Vt[(16 + l15)*VSTR + it*64 + kk*32 + quad*8];
      #pragma unroll
      for (int a = 0; a < 4; a++) {
        short8 Pf = *(const short8*)&pw[(a*16 + l15)*PSTR + kk*32 + quad*8];
        Oa[a][0] = __builtin_amdgcn_mfma_f32_16x16x32_bf16(Pf, Vf0, Oa[a][0], 0, 0, 0);
        Oa[a][1] = __builtin_amdgcn_mfma_f32_16x16x32_bf16(Pf, Vf1, Oa[a][1], 0, 0, 0);
      }
    }
  }

  // ---- normalize and write ----
  float linv[4][4];
  #pragma unroll
  for (int a = 0; a < 4; a++) {
    #pragma unroll
    for (int r = 0; r < 4; r++) {
      float v = lsum[a][r];
      v += __shfl_xor(v, 1);
      v += __shfl_xor(v, 2);
      v += __shfl_xor(v, 4);
      v += __shfl_xor(v, 8);
      linv[a][r] = 1.0f / v;
    }
  }
  float* ob = obuf + ((size_t)i*SS + wv*64) * CC + hh*HD;
  #pragma unroll
  for (int a = 0; a < 4; a++) {
    #pragma unroll
    for (int r = 0; r < 4; r++) {
      int row = (a*16 + quad*4 + r) * CC;
      ob[row + l15]      = Oa[a][0][r] * linv[a][r];
      ob[row + 16 + l15] = Oa[a][1][r] * linv[a][r];
    }
  }
}

// ---------------- gate + output projection: [65536 x 128] x [128 x 128] ----------------
__global__ __launch_bounds__(256) void out_gemm(
    const float* __restrict__ obuf, const float* __restrict__ gbuf,
    const float* __restrict__ wo, float* __restrict__ out) {
  __shared__ float As[16][68];
  __shared__ float Bs[16][68];
  int bm = blockIdx.x * 64;
  int bn = blockIdx.y * 64;
  int tid = threadIdx.x;
  int tr = tid >> 4, tc = tid & 15;
  int lrow = tid >> 2;
  int lk4  = (tid & 3) * 4;
  float acc[4][4] = {};
  for (int k0 = 0; k0 < 128; k0 += 16) {
    float4 a4 = *(const float4*)&obuf[(bm+lrow)*128 + k0 + lk4];
    float4 g4 = *(const float4*)&gbuf[(bm+lrow)*128 + k0 + lk4];
    a4.x *= g4.x; a4.y *= g4.y; a4.z *= g4.z; a4.w *= g4.w;
    float4 b4 = *(const float4*)&wo[(bn+lrow)*128 + k0 + lk4];
    __syncthreads();
    As[lk4+0][lrow]=a4.x; As[lk4+1][lrow]=a4.y; As[lk4+2][lrow]=a4.z; As[lk4+3][lrow]=a4.w;
    Bs[lk4+0][lrow]=b4.x; Bs[lk4+1][lrow]=b4.y; Bs[lk4+2][lrow]=b4.z; Bs[lk4+3][lrow]=b4.w;
    __syncthreads();
    #pragma unroll
    for (int kk = 0; kk < 16; kk++) {
      float ar[4], br[4];
      #pragma unroll
      for (int t = 0; t < 4; t++) { ar[t] = As[kk][tr*4+t]; br[t] = Bs[kk][tc*4+t]; }
      #pragma unroll
      for (int ii = 0; ii < 4; ii++)
        #pragma unroll
        for (int jj = 0; jj < 4; jj++)
          acc[ii][jj] += ar[ii]*br[jj];
    }
  }
  #pragma unroll
  for (int ii = 0; ii < 4; ii++) {
    int m = bm + tr*4 + ii;
    #pragma unroll
    for (int jj = 0; jj < 4; jj++) {
      int n = bn + tc*4 + jj;
      out[m*128 + n] = acc[ii][jj];
    }
  }
}

extern "C" void kernel_launch(void* const* d_in, const int* in_sizes, int n_in,
                              void* d_out, int out_size, void* d_ws, size_t ws_size,
                              hipStream_t stream) {
  const float* x    = (const float*)d_in[0];
  const float* ln_w = (const float*)d_in[1];
  const float* ln_b = (const float*)d_in[2];
  const float* w_bias = (const float*)d_in[3];
  const float* w_q  = (const float*)d_in[4];
  const float* w_k  = (const float*)d_in[5];
  const float* w_v  = (const float*)d_in[6];
  const float* w_g  = (const float*)d_in[7];
  const float* w_o  = (const float*)d_in[8];
  float* out = (float*)d_out;

  float* W = (float*)d_ws;
  float* hbuf  = W;                         // 8388608 f32
  float* gb    = W + 8388608;               // 8388608 f32
  float* biasF = W + 16777216;              // 262144 f32
  float* wcomb = W + 17039360;              // 66048 f32
  unsigned short* qb = (unsigned short*)(W + 17105408);  // 8388608 bf16
  unsigned short* kb = (unsigned short*)(W + 17105408 + 4194304);
  unsigned short* vb = (unsigned short*)(W + 17105408 + 8388608);
  float* obuf  = hbuf;                      // reuse h after projections

  ln_kernel<<<M_TOT, 128, 0, stream>>>(x, ln_w, ln_b, hbuf);
  pack_w<<<(NPROJ*CC + 255)/256, 256, 0, stream>>>(w_q, w_k, w_v, w_g, w_bias, wcomb);
  proj_gemm<<<dim3(M_TOT/64, (NPROJ+63)/64), 256, 0, stream>>>(hbuf, wcomb, qb, kb, vb, gb, biasF);
  attn_mfma<<<dim3(SS, NH), 256, 0, stream>>>(qb, kb, vb, biasF, obuf);
  out_gemm<<<dim3(M_TOT/64, 2), 256, 0, stream>>>(obuf, gb, w_o, out);
}

// Round 3
// 249.199 us; speedup vs baseline: 2.0173x; 1.3631x over previous
//
#include <hip/hip_runtime.h>
#include <hip/hip_bf16.h>
#include <math.h>

#define SS 256
#define CC 128
#define NH 4
#define HD 32
#define M_TOT (SS*SS)       // 65536
#define HEAD_STRIDE (M_TOT*HD)
#define PSTR 72             // padded row stride (elems) for P buffer
#define VSTR 264            // padded row stride (elems) for V^T buffer
#define SCALE 0.17677669529663687f

typedef short short8 __attribute__((ext_vector_type(8)));
typedef float f32x4 __attribute__((ext_vector_type(4)));
typedef unsigned short ushort_t;

static __device__ __forceinline__ unsigned int f2bf(float f) {
  unsigned int u = __builtin_bit_cast(unsigned int, f);
  u += 0x7fffu + ((u >> 16) & 1u);
  return u >> 16;
}
static __device__ __forceinline__ float bf2f(unsigned short b) {
  unsigned int u = ((unsigned int)b) << 16;
  return __builtin_bit_cast(float, u);
}

static __device__ __forceinline__ void async_copy16(const void* g, void* l) {
  __builtin_amdgcn_global_load_lds(
      (const __attribute__((address_space(1))) unsigned int*)g,
      (__attribute__((address_space(3))) unsigned int*)l, 16, 0, 0);
}

// ---------------- LayerNorm (writes bf16 h) ----------------
__global__ __launch_bounds__(128) void ln_kernel(
    const float* __restrict__ x, const float* __restrict__ ln_w,
    const float* __restrict__ ln_b, ushort_t* __restrict__ hbf) {
  int m = blockIdx.x;
  int c = threadIdx.x;
  float v = x[m*CC + c];
  float s = v, s2 = v*v;
  #pragma unroll
  for (int o = 32; o > 0; o >>= 1) {
    s  += __shfl_xor(s, o);
    s2 += __shfl_xor(s2, o);
  }
  __shared__ float red[4];
  int w = c >> 6;
  if ((c & 63) == 0) { red[w*2] = s; red[w*2+1] = s2; }
  __syncthreads();
  s  = red[0] + red[2];
  s2 = red[1] + red[3];
  float mu  = s * (1.0f/CC);
  float var = s2 * (1.0f/CC) - mu*mu;
  float r = rsqrtf(var + 1e-5f);
  hbf[m*CC + c] = (ushort_t)f2bf((v - mu) * r * ln_w[c] + ln_b[c]);
}

// ---------------- pack weights to bf16 ----------------
// wcomb [512][128] (q,k,v,g), wbias_pad [16][128], wo_bf [128][128]
__global__ __launch_bounds__(256) void pack_w(
    const float* __restrict__ wq, const float* __restrict__ wk,
    const float* __restrict__ wv, const float* __restrict__ wg,
    const float* __restrict__ wb, const float* __restrict__ wo,
    ushort_t* __restrict__ wcomb, ushort_t* __restrict__ wbias,
    ushort_t* __restrict__ wobf) {
  int idx = blockIdx.x*256 + threadIdx.x;
  if (idx >= 656*128) return;
  int n = idx >> 7, kk = idx & 127;
  if (n < 512) {
    float val;
    if (n < 128)      val = wq[n*128 + kk];
    else if (n < 256) val = wk[(n-128)*128 + kk];
    else if (n < 384) val = wv[(n-256)*128 + kk];
    else              val = wg[(n-384)*128 + kk];
    wcomb[idx] = (ushort_t)f2bf(val);
  } else if (n < 528) {
    int r = n - 512;
    wbias[r*128 + kk] = (r < NH) ? (ushort_t)f2bf(wb[r*128 + kk]) : (ushort_t)0;
  } else {
    int r = n - 528;
    wobf[r*128 + kk] = (ushort_t)f2bf(wo[r*128 + kk]);
  }
}

// ---------------- MFMA projection GEMM: [65536 x 128] x [128 x 512] ----------------
// blockIdx.y selects section: 0=q,1=k,2=v,3=g. Bias fused into section 0.
__global__ __launch_bounds__(256) void proj_mfma(
    const ushort_t* __restrict__ hbf, const ushort_t* __restrict__ wcomb,
    const ushort_t* __restrict__ wbias,
    ushort_t* __restrict__ qb, ushort_t* __restrict__ kb,
    ushort_t* __restrict__ vb, ushort_t* __restrict__ gbf,
    float* __restrict__ biasP) {
  __shared__ ushort_t Ash[128*128];
  __shared__ ushort_t Bsh[128*128];
  int mbase = blockIdx.x * 128;
  int sec = blockIdx.y;
  int tid = threadIdx.x;
  int wvi = tid >> 6, lane = tid & 63;
  int quad = lane >> 4, l15 = lane & 15;

  // stage A and B tiles, XOR-swizzled (chunk' = chunk ^ (row&7))
  {
    int lrow4 = lane >> 4;        // 0..3 row-within-instruction
    int cl = lane & 15;           // LDS chunk slot
    #pragma unroll
    for (int t = 0; t < 8; t++) {
      int inst = wvi*8 + t;
      int row = inst*4 + lrow4;
      int gc = cl ^ (row & 7);
      async_copy16(hbf + (size_t)(mbase + row)*128 + gc*8, Ash + inst*512);
      async_copy16(wcomb + (size_t)(sec*128 + row)*128 + gc*8, Bsh + inst*512);
    }
  }
  __syncthreads();

  int wrow = (wvi >> 1) * 64, wcol = (wvi & 1) * 64;
  const f32x4 fz = {0.f,0.f,0.f,0.f};
  f32x4 acc[4][4];
  #pragma unroll
  for (int a = 0; a < 4; a++)
    #pragma unroll
    for (int b = 0; b < 4; b++) acc[a][b] = fz;

  #pragma unroll
  for (int s = 0; s < 4; s++) {
    short8 Af[4], Bf[4];
    #pragma unroll
    for (int f = 0; f < 4; f++) {
      int ra = wrow + f*16 + l15;
      Af[f] = *(const short8*)&Ash[ra*128 + (((s*4+quad) ^ (ra&7)) << 3)];
      int rb = wcol + f*16 + l15;
      Bf[f] = *(const short8*)&Bsh[rb*128 + (((s*4+quad) ^ (rb&7)) << 3)];
    }
    #pragma unroll
    for (int mi = 0; mi < 4; mi++)
      #pragma unroll
      for (int ni = 0; ni < 4; ni++)
        acc[mi][ni] = __builtin_amdgcn_mfma_f32_16x16x32_bf16(Af[mi], Bf[ni], acc[mi][ni], 0, 0, 0);
  }

  // epilogue: D row=quad*4+reg <-> m, col=l15 <-> n
  #pragma unroll
  for (int mi = 0; mi < 4; mi++) {
    #pragma unroll
    for (int r = 0; r < 4; r++) {
      int m = mbase + wrow + mi*16 + quad*4 + r;
      #pragma unroll
      for (int ni = 0; ni < 4; ni++) {
        int n = wcol + ni*16 + l15;     // 0..127 within section
        float v = acc[mi][ni][r];
        if (sec == 0) {
          qb[(size_t)(n>>5)*HEAD_STRIDE + (size_t)m*HD + (n&31)] = (ushort_t)f2bf(v);
        } else if (sec == 1) {
          kb[(size_t)(n>>5)*HEAD_STRIDE + (size_t)m*HD + (n&31)] = (ushort_t)f2bf(v);
        } else if (sec == 2) {
          vb[(size_t)(n>>5)*HEAD_STRIDE + (size_t)m*HD + (n&31)] = (ushort_t)f2bf(v);
        } else {
          gbf[(size_t)m*CC + n] = (ushort_t)f2bf(1.0f/(1.0f + __expf(-v)));
        }
      }
    }
  }

  // fused bias GEMV (section 0 only): biasP[head][m], contiguous stores
  if (sec == 0) {
    short8 wbF[4];
    #pragma unroll
    for (int s = 0; s < 4; s++)
      wbF[s] = *(const short8*)&wbias[l15*128 + s*32 + quad*8];
    #pragma unroll
    for (int t2 = 0; t2 < 2; t2++) {
      int f2 = wvi*2 + t2;
      f32x4 bacc = fz;
      #pragma unroll
      for (int s = 0; s < 4; s++) {
        int ra = f2*16 + l15;
        short8 Af = *(const short8*)&Ash[ra*128 + (((s*4+quad) ^ (ra&7)) << 3)];
        bacc = __builtin_amdgcn_mfma_f32_16x16x32_bf16(wbF[s], Af, bacc, 0, 0, 0);
      }
      if (quad == 0) {
        #pragma unroll
        for (int r = 0; r < 4; r++)
          biasP[(size_t)r*M_TOT + mbase + f2*16 + l15] = bacc[r];
      }
    }
  }
}

// ---------------- MFMA attention: one block per (i, h), 4 waves ----------------
__global__ __launch_bounds__(256) void attn_mfma(
    const ushort_t* __restrict__ qb, const ushort_t* __restrict__ kb,
    const ushort_t* __restrict__ vb, const float* __restrict__ biasP,
    const ushort_t* __restrict__ gbf, ushort_t* __restrict__ ogated) {
  __shared__ ushort_t Vt[32*VSTR];       // V^T [d][k], padded
  __shared__ ushort_t Pb[4*64*PSTR];     // per-wave P [j][k], padded
  int i = blockIdx.x, hh = blockIdx.y;
  int tid = threadIdx.x;
  int wvi = tid >> 6, lane = tid & 63;
  int quad = lane >> 4, l15 = lane & 15;

  // ---- stage V^T into LDS (thread t owns key row k=t) ----
  {
    const ushort_t* vrow = vb + ((size_t)hh*M_TOT + (size_t)i*SS + tid) * HD;
    const uint4* v4 = (const uint4*)vrow;
    #pragma unroll
    for (int c = 0; c < 4; c++) {
      uint4 r = v4[c];
      unsigned int u[4] = {r.x, r.y, r.z, r.w};
      #pragma unroll
      for (int w = 0; w < 4; w++) {
        int d = c*8 + w*2;
        Vt[d*VSTR + tid]     = (ushort_t)(u[w] & 0xffffu);
        Vt[(d+1)*VSTR + tid] = (ushort_t)(u[w] >> 16);
      }
    }
  }

  // ---- Q fragments ----
  const ushort_t* qbase = qb + ((size_t)hh*M_TOT + (size_t)i*SS + wvi*64) * HD;
  short8 Qf[4];
  #pragma unroll
  for (int a = 0; a < 4; a++)
    Qf[a] = *(const short8*)(qbase + (a*16 + l15)*HD + quad*8);

  const ushort_t* kbp = kb + ((size_t)hh*M_TOT + (size_t)i*SS) * HD;
  const float* bp = biasP + (size_t)hh*M_TOT;

  const f32x4 fz = {0.f, 0.f, 0.f, 0.f};
  f32x4 Oa[4][2];
  #pragma unroll
  for (int a = 0; a < 4; a++) { Oa[a][0] = fz; Oa[a][1] = fz; }
  float lsum[4][4] = {};

  ushort_t* pw = Pb + wvi*64*PSTR;
  int odd = lane & 1;

  __syncthreads();

  for (int it = 0; it < 4; it++) {
    #pragma unroll
    for (int b = 0; b < 4; b++) {
      int kt = it*4 + b;
      short8 Kf = *(const short8*)(kbp + (kt*16 + l15)*HD + quad*8);
      #pragma unroll
      for (int a = 0; a < 4; a++) {
        f32x4 S = __builtin_amdgcn_mfma_f32_16x16x32_bf16(Qf[a], Kf, fz, 0, 0, 0);
        int jrow = wvi*64 + a*16 + quad*4;
        int kcol = kt*16 + l15;
        float p0 = __expf(S[0]*SCALE + bp[(jrow+0)*SS + kcol]);
        float p1 = __expf(S[1]*SCALE + bp[(jrow+1)*SS + kcol]);
        float p2 = __expf(S[2]*SCALE + bp[(jrow+2)*SS + kcol]);
        float p3 = __expf(S[3]*SCALE + bp[(jrow+3)*SS + kcol]);
        lsum[a][0] += p0; lsum[a][1] += p1; lsum[a][2] += p2; lsum[a][3] += p3;
        unsigned int b0 = f2bf(p0), b1 = f2bf(p1), b2 = f2bf(p2), b3 = f2bf(p3);
        unsigned int o0 = (unsigned int)__shfl_xor((int)b0, 1);
        unsigned int o1 = (unsigned int)__shfl_xor((int)b1, 1);
        unsigned int o2 = (unsigned int)__shfl_xor((int)b2, 1);
        unsigned int o3 = (unsigned int)__shfl_xor((int)b3, 1);
        int jb = a*16 + quad*4;
        int colE = (b*16 + l15) & ~1;
        unsigned int vA = odd ? (o2 | (b2 << 16)) : (b0 | (o0 << 16));
        unsigned int vB = odd ? (o3 | (b3 << 16)) : (b1 | (o1 << 16));
        int rA = jb + (odd ? 2 : 0);
        int rB = jb + (odd ? 3 : 1);
        *(unsigned int*)&pw[rA*PSTR + colE] = vA;
        *(unsigned int*)&pw[rB*PSTR + colE] = vB;
      }
    }
    #pragma unroll
    for (int kk = 0; kk < 2; kk++) {
      short8 Vf0 = *(const short8*)&Vt[(l15)*VSTR      + it*64 + kk*32 + quad*8];
      short8 Vf1 = *(const short8*)&Vt[(16 + l15)*VSTR + it*64 + kk*32 + quad*8];
      #pragma unroll
      for (int a = 0; a < 4; a++) {
        short8 Pf = *(const short8*)&pw[(a*16 + l15)*PSTR + kk*32 + quad*8];
        Oa[a][0] = __builtin_amdgcn_mfma_f32_16x16x32_bf16(Pf, Vf0, Oa[a][0], 0, 0, 0);
        Oa[a][1] = __builtin_amdgcn_mfma_f32_16x16x32_bf16(Pf, Vf1, Oa[a][1], 0, 0, 0);
      }
    }
  }

  // ---- normalize, gate, write bf16 ----
  float linv[4][4];
  #pragma unroll
  for (int a = 0; a < 4; a++) {
    #pragma unroll
    for (int r = 0; r < 4; r++) {
      float v = lsum[a][r];
      v += __shfl_xor(v, 1);
      v += __shfl_xor(v, 2);
      v += __shfl_xor(v, 4);
      v += __shfl_xor(v, 8);
      linv[a][r] = 1.0f / v;
    }
  }
  const ushort_t* gp = gbf + ((size_t)i*SS + wvi*64)*CC + hh*HD;
  ushort_t* ob = ogated + ((size_t)i*SS + wvi*64)*CC + hh*HD;
  #pragma unroll
  for (int a = 0; a < 4; a++) {
    #pragma unroll
    for (int r = 0; r < 4; r++) {
      int row = (a*16 + quad*4 + r) * CC;
      float g0 = bf2f(gp[row + l15]);
      float g1 = bf2f(gp[row + 16 + l15]);
      ob[row + l15]      = (ushort_t)f2bf(Oa[a][0][r] * linv[a][r] * g0);
      ob[row + 16 + l15] = (ushort_t)f2bf(Oa[a][1][r] * linv[a][r] * g1);
    }
  }
}

// ---------------- MFMA output projection: [65536 x 128] x [128 x 128] ----------------
__global__ __launch_bounds__(256) void out_mfma(
    const ushort_t* __restrict__ ogated, const ushort_t* __restrict__ wobf,
    float* __restrict__ out) {
  __shared__ ushort_t Ash[128*128];
  __shared__ ushort_t Bsh[128*128];
  int mbase = blockIdx.x * 128;
  int tid = threadIdx.x;
  int wvi = tid >> 6, lane = tid & 63;
  int quad = lane >> 4, l15 = lane & 15;

  {
    int lrow4 = lane >> 4;
    int cl = lane & 15;
    #pragma unroll
    for (int t = 0; t < 8; t++) {
      int inst = wvi*8 + t;
      int row = inst*4 + lrow4;
      int gc = cl ^ (row & 7);
      async_copy16(ogated + (size_t)(mbase + row)*128 + gc*8, Ash + inst*512);
      async_copy16(wobf + (size_t)row*128 + gc*8, Bsh + inst*512);
    }
  }
  __syncthreads();

  int wrow = (wvi >> 1) * 64, wcol = (wvi & 1) * 64;
  const f32x4 fz = {0.f,0.f,0.f,0.f};
  f32x4 acc[4][4];
  #pragma unroll
  for (int a = 0; a < 4; a++)
    #pragma unroll
    for (int b = 0; b < 4; b++) acc[a][b] = fz;

  #pragma unroll
  for (int s = 0; s < 4; s++) {
    short8 Af[4], Bf[4];
    #pragma unroll
    for (int f = 0; f < 4; f++) {
      int ra = wrow + f*16 + l15;
      Af[f] = *(const short8*)&Ash[ra*128 + (((s*4+quad) ^ (ra&7)) << 3)];
      int rb = wcol + f*16 + l15;
      Bf[f] = *(const short8*)&Bsh[rb*128 + (((s*4+quad) ^ (rb&7)) << 3)];
    }
    #pragma unroll
    for (int mi = 0; mi < 4; mi++)
      #pragma unroll
      for (int ni = 0; ni < 4; ni++)
        acc[mi][ni] = __builtin_amdgcn_mfma_f32_16x16x32_bf16(Af[mi], Bf[ni], acc[mi][ni], 0, 0, 0);
  }

  #pragma unroll
  for (int mi = 0; mi < 4; mi++) {
    #pragma unroll
    for (int r = 0; r < 4; r++) {
      int m = mbase + wrow + mi*16 + quad*4 + r;
      #pragma unroll
      for (int ni = 0; ni < 4; ni++) {
        int n = wcol + ni*16 + l15;
        out[(size_t)m*CC + n] = acc[mi][ni][r];
      }
    }
  }
}

extern "C" void kernel_launch(void* const* d_in, const int* in_sizes, int n_in,
                              void* d_out, int out_size, void* d_ws, size_t ws_size,
                              hipStream_t stream) {
  const float* x    = (const float*)d_in[0];
  const float* ln_w = (const float*)d_in[1];
  const float* ln_b = (const float*)d_in[2];
  const float* w_bias = (const float*)d_in[3];
  const float* w_q  = (const float*)d_in[4];
  const float* w_k  = (const float*)d_in[5];
  const float* w_v  = (const float*)d_in[6];
  const float* w_g  = (const float*)d_in[7];
  const float* w_o  = (const float*)d_in[8];
  float* out = (float*)d_out;

  char* B = (char*)d_ws;
  ushort_t* hbf   = (ushort_t*)(B + 0);           // 16 MB (reused as ogated)
  ushort_t* qb    = (ushort_t*)(B + 16777216);    // 16 MB
  ushort_t* kb    = (ushort_t*)(B + 33554432);    // 16 MB
  ushort_t* vb    = (ushort_t*)(B + 50331648);    // 16 MB
  ushort_t* gbf   = (ushort_t*)(B + 67108864);    // 16 MB
  float*    biasP = (float*)   (B + 83886080);    // 1 MB
  ushort_t* wcomb = (ushort_t*)(B + 84934656);    // 128 KB
  ushort_t* wbias = (ushort_t*)(B + 85065728);    // 4 KB
  ushort_t* wobf  = (ushort_t*)(B + 85069824);    // 32 KB
  ushort_t* ogated = hbf;

  ln_kernel<<<M_TOT, 128, 0, stream>>>(x, ln_w, ln_b, hbf);
  pack_w<<<(656*128 + 255)/256, 256, 0, stream>>>(w_q, w_k, w_v, w_g, w_bias, w_o,
                                                  wcomb, wbias, wobf);
  proj_mfma<<<dim3(M_TOT/128, 4), 256, 0, stream>>>(hbf, wcomb, wbias,
                                                    qb, kb, vb, gbf, biasP);
  attn_mfma<<<dim3(SS, NH), 256, 0, stream>>>(qb, kb, vb, biasP, gbf, ogated);
  out_mfma<<<M_TOT/128, 256, 0, stream>>>(ogated, wobf, out);
}

// Round 4
// 200.581 us; speedup vs baseline: 2.5063x; 1.2424x over previous
//
#include <hip/hip_runtime.h>
#include <hip/hip_bf16.h>
#include <math.h>

#define SS 256
#define CC 128
#define NH 4
#define HD 32
#define M_TOT (SS*SS)       // 65536
#define HEAD_STRIDE (M_TOT*HD)
#define PSTR 72             // padded row stride (elems) for P buffer (x2B=144, 16B-aligned)
#define SCALE 0.17677669529663687f
#define QSCL 0.25507602861154995f   // SCALE * log2(e)
#define LOG2E 1.4426950408889634f

typedef short short8 __attribute__((ext_vector_type(8)));
typedef float f32x4 __attribute__((ext_vector_type(4)));
typedef unsigned short ushort_t;

static __device__ __forceinline__ unsigned int f2bf(float f) {
  unsigned int u = __builtin_bit_cast(unsigned int, f);
  u += 0x7fffu + ((u >> 16) & 1u);
  return u >> 16;
}
static __device__ __forceinline__ float bf2f(unsigned short b) {
  unsigned int u = ((unsigned int)b) << 16;
  return __builtin_bit_cast(float, u);
}

static __device__ __forceinline__ void async_copy16(const void* g, void* l) {
  __builtin_amdgcn_global_load_lds(
      (const __attribute__((address_space(1))) unsigned int*)g,
      (__attribute__((address_space(3))) unsigned int*)l, 16, 0, 0);
}

// ---------------- LayerNorm (writes bf16 h) ----------------
__global__ __launch_bounds__(128) void ln_kernel(
    const float* __restrict__ x, const float* __restrict__ ln_w,
    const float* __restrict__ ln_b, ushort_t* __restrict__ hbf) {
  int m = blockIdx.x;
  int c = threadIdx.x;
  float v = x[m*CC + c];
  float s = v, s2 = v*v;
  #pragma unroll
  for (int o = 32; o > 0; o >>= 1) {
    s  += __shfl_xor(s, o);
    s2 += __shfl_xor(s2, o);
  }
  __shared__ float red[4];
  int w = c >> 6;
  if ((c & 63) == 0) { red[w*2] = s; red[w*2+1] = s2; }
  __syncthreads();
  s  = red[0] + red[2];
  s2 = red[1] + red[3];
  float mu  = s * (1.0f/CC);
  float var = s2 * (1.0f/CC) - mu*mu;
  float r = rsqrtf(var + 1e-5f);
  hbf[m*CC + c] = (ushort_t)f2bf((v - mu) * r * ln_w[c] + ln_b[c]);
}

// ---------------- pack weights to bf16 ----------------
__global__ __launch_bounds__(256) void pack_w(
    const float* __restrict__ wq, const float* __restrict__ wk,
    const float* __restrict__ wv, const float* __restrict__ wg,
    const float* __restrict__ wb, const float* __restrict__ wo,
    ushort_t* __restrict__ wcomb, ushort_t* __restrict__ wbias,
    ushort_t* __restrict__ wobf) {
  int idx = blockIdx.x*256 + threadIdx.x;
  if (idx >= 656*128) return;
  int n = idx >> 7, kk = idx & 127;
  if (n < 512) {
    float val;
    if (n < 128)      val = wq[n*128 + kk];
    else if (n < 256) val = wk[(n-128)*128 + kk];
    else if (n < 384) val = wv[(n-256)*128 + kk];
    else              val = wg[(n-384)*128 + kk];
    wcomb[idx] = (ushort_t)f2bf(val);
  } else if (n < 528) {
    int r = n - 512;
    // bias weights pre-scaled by log2(e) so attention can use exp2
    wbias[r*128 + kk] = (r < NH) ? (ushort_t)f2bf(wb[r*128 + kk] * LOG2E) : (ushort_t)0;
  } else {
    int r = n - 528;
    wobf[r*128 + kk] = (ushort_t)f2bf(wo[r*128 + kk]);
  }
}

// ---------------- MFMA projection GEMM: [65536 x 128] x [128 x 512] ----------------
__global__ __launch_bounds__(256) void proj_mfma(
    const ushort_t* __restrict__ hbf, const ushort_t* __restrict__ wcomb,
    const ushort_t* __restrict__ wbias,
    ushort_t* __restrict__ qb, ushort_t* __restrict__ kb,
    ushort_t* __restrict__ vb, ushort_t* __restrict__ gbf,
    float* __restrict__ biasF) {
  __shared__ ushort_t Ash[128*128];
  __shared__ ushort_t Bsh[128*128];
  int mbase = blockIdx.x * 128;
  int sec = blockIdx.y;
  int tid = threadIdx.x;
  int wvi = tid >> 6, lane = tid & 63;
  int quad = lane >> 4, l15 = lane & 15;

  {
    int lrow4 = lane >> 4;
    int cl = lane & 15;
    #pragma unroll
    for (int t = 0; t < 8; t++) {
      int inst = wvi*8 + t;
      int row = inst*4 + lrow4;
      int gc = cl ^ (row & 7);
      async_copy16(hbf + (size_t)(mbase + row)*128 + gc*8, Ash + inst*512);
      async_copy16(wcomb + (size_t)(sec*128 + row)*128 + gc*8, Bsh + inst*512);
    }
  }
  __syncthreads();

  int wrow = (wvi >> 1) * 64, wcol = (wvi & 1) * 64;
  const f32x4 fz = {0.f,0.f,0.f,0.f};
  f32x4 acc[4][4];
  #pragma unroll
  for (int a = 0; a < 4; a++)
    #pragma unroll
    for (int b = 0; b < 4; b++) acc[a][b] = fz;

  #pragma unroll
  for (int s = 0; s < 4; s++) {
    short8 Af[4], Bf[4];
    #pragma unroll
    for (int f = 0; f < 4; f++) {
      int ra = wrow + f*16 + l15;
      Af[f] = *(const short8*)&Ash[ra*128 + (((s*4+quad) ^ (ra&7)) << 3)];
      int rb = wcol + f*16 + l15;
      Bf[f] = *(const short8*)&Bsh[rb*128 + (((s*4+quad) ^ (rb&7)) << 3)];
    }
    #pragma unroll
    for (int mi = 0; mi < 4; mi++)
      #pragma unroll
      for (int ni = 0; ni < 4; ni++)
        acc[mi][ni] = __builtin_amdgcn_mfma_f32_16x16x32_bf16(Af[mi], Bf[ni], acc[mi][ni], 0, 0, 0);
  }

  #pragma unroll
  for (int mi = 0; mi < 4; mi++) {
    #pragma unroll
    for (int r = 0; r < 4; r++) {
      int m = mbase + wrow + mi*16 + quad*4 + r;
      #pragma unroll
      for (int ni = 0; ni < 4; ni++) {
        int n = wcol + ni*16 + l15;
        float v = acc[mi][ni][r];
        if (sec == 0) {
          // q pre-scaled by SCALE*log2e so attention mfma+exp2 needs no VALU fixup
          qb[(size_t)(n>>5)*HEAD_STRIDE + (size_t)m*HD + (n&31)] = (ushort_t)f2bf(v * QSCL);
        } else if (sec == 1) {
          kb[(size_t)(n>>5)*HEAD_STRIDE + (size_t)m*HD + (n&31)] = (ushort_t)f2bf(v);
        } else if (sec == 2) {
          vb[(size_t)(n>>5)*HEAD_STRIDE + (size_t)m*HD + (n&31)] = (ushort_t)f2bf(v);
        } else {
          gbf[(size_t)m*CC + n] = (ushort_t)f2bf(1.0f/(1.0f + __expf(-v)));
        }
      }
    }
  }

  // fused bias GEMV (section 0): store bias*log2e in MFMA C-fragment order
  if (sec == 0) {
    short8 wbF[4];
    #pragma unroll
    for (int s = 0; s < 4; s++)
      wbF[s] = *(const short8*)&wbias[l15*128 + s*32 + quad*8];
    #pragma unroll
    for (int t2 = 0; t2 < 2; t2++) {
      int f2 = wvi*2 + t2;
      f32x4 bacc = fz;
      #pragma unroll
      for (int s = 0; s < 4; s++) {
        int ra = f2*16 + l15;
        short8 Af = *(const short8*)&Ash[ra*128 + (((s*4+quad) ^ (ra&7)) << 3)];
        bacc = __builtin_amdgcn_mfma_f32_16x16x32_bf16(wbF[s], Af, bacc, 0, 0, 0);
      }
      if (quad == 0) {
        int m = mbase + f2*16 + l15;
        int ji = m >> 8, ki = m & 255;
        int jt = ji >> 4, q2 = (ji >> 2) & 3, rg = ji & 3;
        int kt = ki >> 4, lf = ki & 15;
        #pragma unroll
        for (int r = 0; r < 4; r++)
          biasF[(size_t)(((r*16 + jt)*16 + kt) << 8) + (q2*16 + lf)*4 + rg] = bacc[r];
      }
    }
  }
}

// ---------------- MFMA attention: one block per (i, h), 4 waves, 3 blocks/CU ----------------
__global__ __launch_bounds__(256, 3) void attn_mfma(
    const ushort_t* __restrict__ qb, const ushort_t* __restrict__ kb,
    const ushort_t* __restrict__ vb, const float* __restrict__ biasF,
    const ushort_t* __restrict__ gbf, ushort_t* __restrict__ ogated) {
  __shared__ ushort_t Vt[32*256];        // V^T [d][k], XOR-swizzled chunks (16 KB)
  __shared__ ushort_t Pb[4*64*PSTR];     // per-wave P [j][k], padded (36 KB)
  int i = blockIdx.x, hh = blockIdx.y;
  int tid = threadIdx.x;
  int wvi = tid >> 6, lane = tid & 63;
  int quad = lane >> 4, l15 = lane & 15;

  // ---- stage V^T into LDS (thread t owns key row k=t), chunk-XOR swizzle ----
  {
    const ushort_t* vrow = vb + ((size_t)hh*M_TOT + (size_t)i*SS + tid) * HD;
    const uint4* v4 = (const uint4*)vrow;
    int cs = tid >> 3, ce = tid & 7;
    #pragma unroll
    for (int c = 0; c < 4; c++) {
      uint4 r = v4[c];
      unsigned int u[4] = {r.x, r.y, r.z, r.w};
      #pragma unroll
      for (int w = 0; w < 4; w++) {
        int d = c*8 + w*2;
        Vt[d*256     + ((cs ^ (d&7))     << 3) + ce] = (ushort_t)(u[w] & 0xffffu);
        Vt[(d+1)*256 + ((cs ^ ((d+1)&7)) << 3) + ce] = (ushort_t)(u[w] >> 16);
      }
    }
  }

  // ---- Q fragments (pre-scaled by SCALE*log2e) ----
  const ushort_t* qbase = qb + ((size_t)hh*M_TOT + (size_t)i*SS + wvi*64) * HD;
  short8 Qf[4];
  #pragma unroll
  for (int a = 0; a < 4; a++)
    Qf[a] = *(const short8*)(qbase + (a*16 + l15)*HD + quad*8);

  const ushort_t* kbp = kb + ((size_t)hh*M_TOT + (size_t)i*SS) * HD;
  const float* bb = biasF + (size_t)(hh*16 + wvi*4) * 4096;

  const f32x4 fz = {0.f, 0.f, 0.f, 0.f};
  f32x4 Oa[4][2];
  #pragma unroll
  for (int a = 0; a < 4; a++) { Oa[a][0] = fz; Oa[a][1] = fz; }
  float lsum[4][4] = {};

  ushort_t* pw = Pb + wvi*64*PSTR;

  __syncthreads();

  #pragma unroll
  for (int it = 0; it < 4; it++) {
    #pragma unroll
    for (int b = 0; b < 4; b++) {
      int kt = it*4 + b;
      short8 Kf = *(const short8*)(kbp + (kt*16 + l15)*HD + quad*8);
      #pragma unroll
      for (int a = 0; a < 4; a++) {
        float4 bt = *(const float4*)(bb + (size_t)((a*16 + kt) << 8) + lane*4);
        f32x4 bias4 = {bt.x, bt.y, bt.z, bt.w};
        f32x4 S = __builtin_amdgcn_mfma_f32_16x16x32_bf16(Qf[a], Kf, bias4, 0, 0, 0);
        float p0 = __builtin_amdgcn_exp2f(S[0]);
        float p1 = __builtin_amdgcn_exp2f(S[1]);
        float p2 = __builtin_amdgcn_exp2f(S[2]);
        float p3 = __builtin_amdgcn_exp2f(S[3]);
        lsum[a][0] += p0; lsum[a][1] += p1; lsum[a][2] += p2; lsum[a][3] += p3;
        ushort_t* pwa = pw + (a*16 + quad*4)*PSTR + b*16 + l15;
        pwa[0*PSTR] = (ushort_t)f2bf(p0);
        pwa[1*PSTR] = (ushort_t)f2bf(p1);
        pwa[2*PSTR] = (ushort_t)f2bf(p2);
        pwa[3*PSTR] = (ushort_t)f2bf(p3);
      }
    }
    // P·V for this 64-wide k chunk (wave-private P; same-wave DS ordering)
    #pragma unroll
    for (int kk = 0; kk < 2; kk++) {
      int cb = it*8 + kk*4;
      int sw = ((cb + quad) ^ (l15 & 7)) << 3;
      short8 Vf0 = *(const short8*)&Vt[l15*256 + sw];
      short8 Vf1 = *(const short8*)&Vt[(16 + l15)*256 + sw];
      #pragma unroll
      for (int a = 0; a < 4; a++) {
        short8 Pf = *(const short8*)&pw[(a*16 + l15)*PSTR + kk*32 + quad*8];
        Oa[a][0] = __builtin_amdgcn_mfma_f32_16x16x32_bf16(Pf, Vf0, Oa[a][0], 0, 0, 0);
        Oa[a][1] = __builtin_amdgcn_mfma_f32_16x16x32_bf16(Pf, Vf1, Oa[a][1], 0, 0, 0);
      }
    }
  }

  // ---- normalize, gate, write bf16 ----
  float linv[4][4];
  #pragma unroll
  for (int a = 0; a < 4; a++) {
    #pragma unroll
    for (int r = 0; r < 4; r++) {
      float v = lsum[a][r];
      v += __shfl_xor(v, 1);
      v += __shfl_xor(v, 2);
      v += __shfl_xor(v, 4);
      v += __shfl_xor(v, 8);
      linv[a][r] = 1.0f / v;
    }
  }
  const ushort_t* gp = gbf + ((size_t)i*SS + wvi*64)*CC + hh*HD;
  ushort_t* ob = ogated + ((size_t)i*SS + wvi*64)*CC + hh*HD;
  #pragma unroll
  for (int a = 0; a < 4; a++) {
    #pragma unroll
    for (int r = 0; r < 4; r++) {
      int row = (a*16 + quad*4 + r) * CC;
      float g0 = bf2f(gp[row + l15]);
      float g1 = bf2f(gp[row + 16 + l15]);
      ob[row + l15]      = (ushort_t)f2bf(Oa[a][0][r] * linv[a][r] * g0);
      ob[row + 16 + l15] = (ushort_t)f2bf(Oa[a][1][r] * linv[a][r] * g1);
    }
  }
}

// ---------------- MFMA output projection: [65536 x 128] x [128 x 128] ----------------
__global__ __launch_bounds__(256) void out_mfma(
    const ushort_t* __restrict__ ogated, const ushort_t* __restrict__ wobf,
    float* __restrict__ out) {
  __shared__ ushort_t Ash[128*128];
  __shared__ ushort_t Bsh[128*128];
  int mbase = blockIdx.x * 128;
  int tid = threadIdx.x;
  int wvi = tid >> 6, lane = tid & 63;
  int quad = lane >> 4, l15 = lane & 15;

  {
    int lrow4 = lane >> 4;
    int cl = lane & 15;
    #pragma unroll
    for (int t = 0; t < 8; t++) {
      int inst = wvi*8 + t;
      int row = inst*4 + lrow4;
      int gc = cl ^ (row & 7);
      async_copy16(ogated + (size_t)(mbase + row)*128 + gc*8, Ash + inst*512);
      async_copy16(wobf + (size_t)row*128 + gc*8, Bsh + inst*512);
    }
  }
  __syncthreads();

  int wrow = (wvi >> 1) * 64, wcol = (wvi & 1) * 64;
  const f32x4 fz = {0.f,0.f,0.f,0.f};
  f32x4 acc[4][4];
  #pragma unroll
  for (int a = 0; a < 4; a++)
    #pragma unroll
    for (int b = 0; b < 4; b++) acc[a][b] = fz;

  #pragma unroll
  for (int s = 0; s < 4; s++) {
    short8 Af[4], Bf[4];
    #pragma unroll
    for (int f = 0; f < 4; f++) {
      int ra = wrow + f*16 + l15;
      Af[f] = *(const short8*)&Ash[ra*128 + (((s*4+quad) ^ (ra&7)) << 3)];
      int rb = wcol + f*16 + l15;
      Bf[f] = *(const short8*)&Bsh[rb*128 + (((s*4+quad) ^ (rb&7)) << 3)];
    }
    #pragma unroll
    for (int mi = 0; mi < 4; mi++)
      #pragma unroll
      for (int ni = 0; ni < 4; ni++)
        acc[mi][ni] = __builtin_amdgcn_mfma_f32_16x16x32_bf16(Af[mi], Bf[ni], acc[mi][ni], 0, 0, 0);
  }

  #pragma unroll
  for (int mi = 0; mi < 4; mi++) {
    #pragma unroll
    for (int r = 0; r < 4; r++) {
      int m = mbase + wrow + mi*16 + quad*4 + r;
      #pragma unroll
      for (int ni = 0; ni < 4; ni++) {
        int n = wcol + ni*16 + l15;
        out[(size_t)m*CC + n] = acc[mi][ni][r];
      }
    }
  }
}

extern "C" void kernel_launch(void* const* d_in, const int* in_sizes, int n_in,
                              void* d_out, int out_size, void* d_ws, size_t ws_size,
                              hipStream_t stream) {
  const float* x    = (const float*)d_in[0];
  const float* ln_w = (const float*)d_in[1];
  const float* ln_b = (const float*)d_in[2];
  const float* w_bias = (const float*)d_in[3];
  const float* w_q  = (const float*)d_in[4];
  const float* w_k  = (const float*)d_in[5];
  const float* w_v  = (const float*)d_in[6];
  const float* w_g  = (const float*)d_in[7];
  const float* w_o  = (const float*)d_in[8];
  float* out = (float*)d_out;

  char* B = (char*)d_ws;
  ushort_t* hbf   = (ushort_t*)(B + 0);           // 16 MB (reused as ogated)
  ushort_t* qb    = (ushort_t*)(B + 16777216);    // 16 MB
  ushort_t* kb    = (ushort_t*)(B + 33554432);    // 16 MB
  ushort_t* vb    = (ushort_t*)(B + 50331648);    // 16 MB
  ushort_t* gbf   = (ushort_t*)(B + 67108864);    // 16 MB
  float*    biasF = (float*)   (B + 83886080);    // 1 MB
  ushort_t* wcomb = (ushort_t*)(B + 84934656);    // 128 KB
  ushort_t* wbias = (ushort_t*)(B + 85065728);    // 4 KB
  ushort_t* wobf  = (ushort_t*)(B + 85069824);    // 32 KB
  ushort_t* ogated = hbf;

  ln_kernel<<<M_TOT, 128, 0, stream>>>(x, ln_w, ln_b, hbf);
  pack_w<<<(656*128 + 255)/256, 256, 0, stream>>>(w_q, w_k, w_v, w_g, w_bias, w_o,
                                                  wcomb, wbias, wobf);
  proj_mfma<<<dim3(M_TOT/128, 4), 256, 0, stream>>>(hbf, wcomb, wbias,
                                                    qb, kb, vb, gbf, biasF);
  attn_mfma<<<dim3(SS, NH), 256, 0, stream>>>(qb, kb, vb, biasF, gbf, ogated);
  out_mfma<<<M_TOT/128, 256, 0, stream>>>(ogated, wobf, out);
}

// Round 5
// 187.934 us; speedup vs baseline: 2.6749x; 1.0673x over previous
//
#include <hip/hip_runtime.h>
#include <hip/hip_bf16.h>
#include <math.h>

#define SS 256
#define CC 128
#define NH 4
#define HD 32
#define M_TOT (SS*SS)       // 65536
#define HEAD_STRIDE (M_TOT*HD)
#define PSTR 72             // padded row stride (elems) for P buffer
#define SCALE 0.17677669529663687f
#define QSCL 0.25507602861154995f   // SCALE * log2(e)
#define LOG2E 1.4426950408889634f

typedef short short8 __attribute__((ext_vector_type(8)));
typedef float f32x4 __attribute__((ext_vector_type(4)));
typedef unsigned short ushort_t;

static __device__ __forceinline__ unsigned int f2bf(float f) {
  unsigned int u = __builtin_bit_cast(unsigned int, f);
  u += 0x7fffu + ((u >> 16) & 1u);
  return u >> 16;
}
static __device__ __forceinline__ float bf2f(unsigned short b) {
  unsigned int u = ((unsigned int)b) << 16;
  return __builtin_bit_cast(float, u);
}

static __device__ __forceinline__ void async_copy16(const void* g, void* l) {
  __builtin_amdgcn_global_load_lds(
      (const __attribute__((address_space(1))) unsigned int*)g,
      (__attribute__((address_space(3))) unsigned int*)l, 16, 0, 0);
}

// ---------------- LayerNorm (vectorized: 32 lanes/row, float4 in, ushort4 out) ----------------
__global__ __launch_bounds__(256) void ln_kernel(
    const float* __restrict__ x, const float* __restrict__ ln_w,
    const float* __restrict__ ln_b, ushort_t* __restrict__ hbf) {
  int t = threadIdx.x;
  int row = blockIdx.x*8 + (t >> 5);
  int l = t & 31;
  float4 v = *(const float4*)&x[(size_t)row*CC + l*4];
  float s  = v.x + v.y + v.z + v.w;
  float s2 = v.x*v.x + v.y*v.y + v.z*v.z + v.w*v.w;
  #pragma unroll
  for (int o = 16; o > 0; o >>= 1) {
    s  += __shfl_xor(s, o);
    s2 += __shfl_xor(s2, o);
  }
  float mu  = s * (1.0f/CC);
  float var = s2 * (1.0f/CC) - mu*mu;
  float r = rsqrtf(var + 1e-5f);
  float4 w4 = *(const float4*)&ln_w[l*4];
  float4 b4 = *(const float4*)&ln_b[l*4];
  ushort4 o4;
  o4.x = (ushort_t)f2bf((v.x - mu) * r * w4.x + b4.x);
  o4.y = (ushort_t)f2bf((v.y - mu) * r * w4.y + b4.y);
  o4.z = (ushort_t)f2bf((v.z - mu) * r * w4.z + b4.z);
  o4.w = (ushort_t)f2bf((v.w - mu) * r * w4.w + b4.w);
  *(ushort4*)&hbf[(size_t)row*CC + l*4] = o4;
}

// ---------------- pack weights to bf16 ----------------
__global__ __launch_bounds__(256) void pack_w(
    const float* __restrict__ wq, const float* __restrict__ wk,
    const float* __restrict__ wv, const float* __restrict__ wg,
    const float* __restrict__ wb, const float* __restrict__ wo,
    ushort_t* __restrict__ wcomb, ushort_t* __restrict__ wbias,
    ushort_t* __restrict__ wobf) {
  int idx = blockIdx.x*256 + threadIdx.x;
  if (idx >= 656*128) return;
  int n = idx >> 7, kk = idx & 127;
  if (n < 512) {
    float val;
    if (n < 128)      val = wq[n*128 + kk];
    else if (n < 256) val = wk[(n-128)*128 + kk];
    else if (n < 384) val = wv[(n-256)*128 + kk];
    else              val = wg[(n-384)*128 + kk];
    wcomb[idx] = (ushort_t)f2bf(val);
  } else if (n < 528) {
    int r = n - 512;
    wbias[r*128 + kk] = (r < NH) ? (ushort_t)f2bf(wb[r*128 + kk] * LOG2E) : (ushort_t)0;
  } else {
    int r = n - 528;
    wobf[r*128 + kk] = (ushort_t)f2bf(wo[r*128 + kk]);
  }
}

// ---------------- MFMA projection GEMM: [65536 x 128] x [128 x 512] ----------------
// B (one 128x128 section) in LDS; A fragments loaded direct global->VGPR.
__global__ __launch_bounds__(256, 3) void proj_mfma(
    const ushort_t* __restrict__ hbf, const ushort_t* __restrict__ wcomb,
    const ushort_t* __restrict__ wbias,
    ushort_t* __restrict__ qb, ushort_t* __restrict__ kb,
    ushort_t* __restrict__ vb, ushort_t* __restrict__ gbf,
    float* __restrict__ biasF) {
  __shared__ ushort_t Bsh[128*128];   // 32 KB
  int mbase = blockIdx.x * 128;
  int sec = blockIdx.y;
  int tid = threadIdx.x;
  int wvi = tid >> 6, lane = tid & 63;
  int quad = lane >> 4, l15 = lane & 15;

  {
    int lrow4 = lane >> 4;
    int cl = lane & 15;
    #pragma unroll
    for (int t = 0; t < 8; t++) {
      int inst = wvi*8 + t;
      int row = inst*4 + lrow4;
      int gc = cl ^ (row & 7);
      async_copy16(wcomb + (size_t)(sec*128 + row)*128 + gc*8, Bsh + inst*512);
    }
  }
  __syncthreads();

  int wrow = (wvi >> 1) * 64, wcol = (wvi & 1) * 64;
  const f32x4 fz = {0.f,0.f,0.f,0.f};
  f32x4 acc[4][4];
  #pragma unroll
  for (int a = 0; a < 4; a++)
    #pragma unroll
    for (int b = 0; b < 4; b++) acc[a][b] = fz;

  #pragma unroll
  for (int s = 0; s < 4; s++) {
    short8 Af[4], Bf[4];
    #pragma unroll
    for (int f = 0; f < 4; f++) {
      int ra = mbase + wrow + f*16 + l15;
      Af[f] = *(const short8*)&hbf[(size_t)ra*128 + s*32 + quad*8];
      int rb = wcol + f*16 + l15;
      Bf[f] = *(const short8*)&Bsh[rb*128 + (((s*4+quad) ^ (rb&7)) << 3)];
    }
    #pragma unroll
    for (int mi = 0; mi < 4; mi++)
      #pragma unroll
      for (int ni = 0; ni < 4; ni++)
        acc[mi][ni] = __builtin_amdgcn_mfma_f32_16x16x32_bf16(Af[mi], Bf[ni], acc[mi][ni], 0, 0, 0);
  }

  #pragma unroll
  for (int mi = 0; mi < 4; mi++) {
    #pragma unroll
    for (int r = 0; r < 4; r++) {
      int m = mbase + wrow + mi*16 + quad*4 + r;
      #pragma unroll
      for (int ni = 0; ni < 4; ni++) {
        int n = wcol + ni*16 + l15;
        float v = acc[mi][ni][r];
        if (sec == 0) {
          qb[(size_t)(n>>5)*HEAD_STRIDE + (size_t)m*HD + (n&31)] = (ushort_t)f2bf(v * QSCL);
        } else if (sec == 1) {
          kb[(size_t)(n>>5)*HEAD_STRIDE + (size_t)m*HD + (n&31)] = (ushort_t)f2bf(v);
        } else if (sec == 2) {
          vb[(size_t)(n>>5)*HEAD_STRIDE + (size_t)m*HD + (n&31)] = (ushort_t)f2bf(v);
        } else {
          gbf[(size_t)m*CC + n] = (ushort_t)f2bf(1.0f/(1.0f + __expf(-v)));
        }
      }
    }
  }

  // fused bias GEMV (section 0): bias*log2e in MFMA C-fragment order
  if (sec == 0) {
    short8 wbF[4];
    #pragma unroll
    for (int s = 0; s < 4; s++)
      wbF[s] = *(const short8*)&wbias[l15*128 + s*32 + quad*8];
    #pragma unroll
    for (int t2 = 0; t2 < 2; t2++) {
      int f2 = wvi*2 + t2;
      f32x4 bacc = fz;
      #pragma unroll
      for (int s = 0; s < 4; s++) {
        short8 Af = *(const short8*)&hbf[(size_t)(mbase + f2*16 + l15)*128 + s*32 + quad*8];
        bacc = __builtin_amdgcn_mfma_f32_16x16x32_bf16(wbF[s], Af, bacc, 0, 0, 0);
      }
      if (quad == 0) {
        int m = mbase + f2*16 + l15;
        int ji = m >> 8, ki = m & 255;
        int jt = ji >> 4, q2 = (ji >> 2) & 3, rg = ji & 3;
        int kt = ki >> 4, lf = ki & 15;
        #pragma unroll
        for (int r = 0; r < 4; r++)
          biasF[(size_t)(((r*16 + jt)*16 + kt) << 8) + (q2*16 + lf)*4 + rg] = bacc[r];
      }
    }
  }
}

// ---------------- MFMA attention: one block per (i, h), 4 waves, 3 blocks/CU ----------------
__global__ __launch_bounds__(256, 3) void attn_mfma(
    const ushort_t* __restrict__ qb, const ushort_t* __restrict__ kb,
    const ushort_t* __restrict__ vb, const float* __restrict__ biasF,
    const ushort_t* __restrict__ gbf, ushort_t* __restrict__ ogated) {
  __shared__ ushort_t Vt[32*256];        // V^T [d][k], XOR-swizzled chunks (16 KB)
  __shared__ ushort_t Pb[4*64*PSTR];     // per-wave P [j][k], padded (36 KB)
  int i = blockIdx.x, hh = blockIdx.y;
  int tid = threadIdx.x;
  int wvi = tid >> 6, lane = tid & 63;
  int quad = lane >> 4, l15 = lane & 15;

  {
    const ushort_t* vrow = vb + ((size_t)hh*M_TOT + (size_t)i*SS + tid) * HD;
    const uint4* v4 = (const uint4*)vrow;
    int cs = tid >> 3, ce = tid & 7;
    #pragma unroll
    for (int c = 0; c < 4; c++) {
      uint4 r = v4[c];
      unsigned int u[4] = {r.x, r.y, r.z, r.w};
      #pragma unroll
      for (int w = 0; w < 4; w++) {
        int d = c*8 + w*2;
        Vt[d*256     + ((cs ^ (d&7))     << 3) + ce] = (ushort_t)(u[w] & 0xffffu);
        Vt[(d+1)*256 + ((cs ^ ((d+1)&7)) << 3) + ce] = (ushort_t)(u[w] >> 16);
      }
    }
  }

  const ushort_t* qbase = qb + ((size_t)hh*M_TOT + (size_t)i*SS + wvi*64) * HD;
  short8 Qf[4];
  #pragma unroll
  for (int a = 0; a < 4; a++)
    Qf[a] = *(const short8*)(qbase + (a*16 + l15)*HD + quad*8);

  const ushort_t* kbp = kb + ((size_t)hh*M_TOT + (size_t)i*SS) * HD;
  const float* bb = biasF + (size_t)(hh*16 + wvi*4) * 4096;

  const f32x4 fz = {0.f, 0.f, 0.f, 0.f};
  f32x4 Oa[4][2];
  #pragma unroll
  for (int a = 0; a < 4; a++) { Oa[a][0] = fz; Oa[a][1] = fz; }
  float lsum[4][4] = {};

  ushort_t* pw = Pb + wvi*64*PSTR;

  __syncthreads();

  #pragma unroll
  for (int it = 0; it < 4; it++) {
    #pragma unroll
    for (int b = 0; b < 4; b++) {
      int kt = it*4 + b;
      short8 Kf = *(const short8*)(kbp + (kt*16 + l15)*HD + quad*8);
      #pragma unroll
      for (int a = 0; a < 4; a++) {
        float4 bt = *(const float4*)(bb + (size_t)((a*16 + kt) << 8) + lane*4);
        f32x4 bias4 = {bt.x, bt.y, bt.z, bt.w};
        f32x4 S = __builtin_amdgcn_mfma_f32_16x16x32_bf16(Qf[a], Kf, bias4, 0, 0, 0);
        float p0 = __builtin_amdgcn_exp2f(S[0]);
        float p1 = __builtin_amdgcn_exp2f(S[1]);
        float p2 = __builtin_amdgcn_exp2f(S[2]);
        float p3 = __builtin_amdgcn_exp2f(S[3]);
        lsum[a][0] += p0; lsum[a][1] += p1; lsum[a][2] += p2; lsum[a][3] += p3;
        ushort_t* pwa = pw + (a*16 + quad*4)*PSTR + b*16 + l15;
        pwa[0*PSTR] = (ushort_t)f2bf(p0);
        pwa[1*PSTR] = (ushort_t)f2bf(p1);
        pwa[2*PSTR] = (ushort_t)f2bf(p2);
        pwa[3*PSTR] = (ushort_t)f2bf(p3);
      }
    }
    #pragma unroll
    for (int kk = 0; kk < 2; kk++) {
      int cb = it*8 + kk*4;
      int sw = ((cb + quad) ^ (l15 & 7)) << 3;
      short8 Vf0 = *(const short8*)&Vt[l15*256 + sw];
      short8 Vf1 = *(const short8*)&Vt[(16 + l15)*256 + sw];
      #pragma unroll
      for (int a = 0; a < 4; a++) {
        short8 Pf = *(const short8*)&pw[(a*16 + l15)*PSTR + kk*32 + quad*8];
        Oa[a][0] = __builtin_amdgcn_mfma_f32_16x16x32_bf16(Pf, Vf0, Oa[a][0], 0, 0, 0);
        Oa[a][1] = __builtin_amdgcn_mfma_f32_16x16x32_bf16(Pf, Vf1, Oa[a][1], 0, 0, 0);
      }
    }
  }

  float linv[4][4];
  #pragma unroll
  for (int a = 0; a < 4; a++) {
    #pragma unroll
    for (int r = 0; r < 4; r++) {
      float v = lsum[a][r];
      v += __shfl_xor(v, 1);
      v += __shfl_xor(v, 2);
      v += __shfl_xor(v, 4);
      v += __shfl_xor(v, 8);
      linv[a][r] = 1.0f / v;
    }
  }
  const ushort_t* gp = gbf + ((size_t)i*SS + wvi*64)*CC + hh*HD;
  ushort_t* ob = ogated + ((size_t)i*SS + wvi*64)*CC + hh*HD;
  #pragma unroll
  for (int a = 0; a < 4; a++) {
    #pragma unroll
    for (int r = 0; r < 4; r++) {
      int row = (a*16 + quad*4 + r) * CC;
      float g0 = bf2f(gp[row + l15]);
      float g1 = bf2f(gp[row + 16 + l15]);
      ob[row + l15]      = (ushort_t)f2bf(Oa[a][0][r] * linv[a][r] * g0);
      ob[row + 16 + l15] = (ushort_t)f2bf(Oa[a][1][r] * linv[a][r] * g1);
    }
  }
}

// ---------------- MFMA output projection: [65536 x 128] x [128 x 128] ----------------
__global__ __launch_bounds__(256, 3) void out_mfma(
    const ushort_t* __restrict__ ogated, const ushort_t* __restrict__ wobf,
    float* __restrict__ out) {
  __shared__ ushort_t Bsh[128*128];   // 32 KB
  int mbase = blockIdx.x * 128;
  int tid = threadIdx.x;
  int wvi = tid >> 6, lane = tid & 63;
  int quad = lane >> 4, l15 = lane & 15;

  {
    int lrow4 = lane >> 4;
    int cl = lane & 15;
    #pragma unroll
    for (int t = 0; t < 8; t++) {
      int inst = wvi*8 + t;
      int row = inst*4 + lrow4;
      int gc = cl ^ (row & 7);
      async_copy16(wobf + (size_t)row*128 + gc*8, Bsh + inst*512);
    }
  }
  __syncthreads();

  int wrow = (wvi >> 1) * 64, wcol = (wvi & 1) * 64;
  const f32x4 fz = {0.f,0.f,0.f,0.f};
  f32x4 acc[4][4];
  #pragma unroll
  for (int a = 0; a < 4; a++)
    #pragma unroll
    for (int b = 0; b < 4; b++) acc[a][b] = fz;

  #pragma unroll
  for (int s = 0; s < 4; s++) {
    short8 Af[4], Bf[4];
    #pragma unroll
    for (int f = 0; f < 4; f++) {
      int ra = mbase + wrow + f*16 + l15;
      Af[f] = *(const short8*)&ogated[(size_t)ra*128 + s*32 + quad*8];
      int rb = wcol + f*16 + l15;
      Bf[f] = *(const short8*)&Bsh[rb*128 + (((s*4+quad) ^ (rb&7)) << 3)];
    }
    #pragma unroll
    for (int mi = 0; mi < 4; mi++)
      #pragma unroll
      for (int ni = 0; ni < 4; ni++)
        acc[mi][ni] = __builtin_amdgcn_mfma_f32_16x16x32_bf16(Af[mi], Bf[ni], acc[mi][ni], 0, 0, 0);
  }

  #pragma unroll
  for (int mi = 0; mi < 4; mi++) {
    #pragma unroll
    for (int r = 0; r < 4; r++) {
      int m = mbase + wrow + mi*16 + quad*4 + r;
      #pragma unroll
      for (int ni = 0; ni < 4; ni++) {
        int n = wcol + ni*16 + l15;
        out[(size_t)m*CC + n] = acc[mi][ni][r];
      }
    }
  }
}

extern "C" void kernel_launch(void* const* d_in, const int* in_sizes, int n_in,
                              void* d_out, int out_size, void* d_ws, size_t ws_size,
                              hipStream_t stream) {
  const float* x    = (const float*)d_in[0];
  const float* ln_w = (const float*)d_in[1];
  const float* ln_b = (const float*)d_in[2];
  const float* w_bias = (const float*)d_in[3];
  const float* w_q  = (const float*)d_in[4];
  const float* w_k  = (const float*)d_in[5];
  const float* w_v  = (const float*)d_in[6];
  const float* w_g  = (const float*)d_in[7];
  const float* w_o  = (const float*)d_in[8];
  float* out = (float*)d_out;

  char* B = (char*)d_ws;
  ushort_t* hbf   = (ushort_t*)(B + 0);           // 16 MB (reused as ogated)
  ushort_t* qb    = (ushort_t*)(B + 16777216);    // 16 MB
  ushort_t* kb    = (ushort_t*)(B + 33554432);    // 16 MB
  ushort_t* vb    = (ushort_t*)(B + 50331648);    // 16 MB
  ushort_t* gbf   = (ushort_t*)(B + 67108864);    // 16 MB
  float*    biasF = (float*)   (B + 83886080);    // 1 MB
  ushort_t* wcomb = (ushort_t*)(B + 84934656);    // 128 KB
  ushort_t* wbias = (ushort_t*)(B + 85065728);    // 4 KB
  ushort_t* wobf  = (ushort_t*)(B + 85069824);    // 32 KB
  ushort_t* ogated = hbf;

  ln_kernel<<<M_TOT/8, 256, 0, stream>>>(x, ln_w, ln_b, hbf);
  pack_w<<<(656*128 + 255)/256, 256, 0, stream>>>(w_q, w_k, w_v, w_g, w_bias, w_o,
                                                  wcomb, wbias, wobf);
  proj_mfma<<<dim3(M_TOT/128, 4), 256, 0, stream>>>(hbf, wcomb, wbias,
                                                    qb, kb, vb, gbf, biasF);
  attn_mfma<<<dim3(SS, NH), 256, 0, stream>>>(qb, kb, vb, biasF, gbf, ogated);
  out_mfma<<<M_TOT/128, 256, 0, stream>>>(ogated, wobf, out);
}